// Round 10
// baseline (1115.263 us; speedup 1.0000x reference)
//
#include <hip/hip_runtime.h>

#define PROP_ALPHA 0.1f
#define PROP_KSTEPS 10

typedef _Float16 half_t;
typedef __attribute__((ext_vector_type(4))) _Float16 half4v;
typedef __attribute__((ext_vector_type(8))) _Float16 half8v;
typedef __attribute__((ext_vector_type(4))) float f32x4;

// ---------------- CSR build ----------------

__global__ void hist_kernel(const int* __restrict__ dst, int* __restrict__ degI, int E) {
    int e = blockIdx.x * blockDim.x + threadIdx.x;
    if (e < E) atomicAdd(&degI[dst[e]], 1);
}

// dinv over N+1 (row N = zero sink for pad slots); also zero vA[N]/vB[N]
__global__ void dinvz_kernel(const int* __restrict__ degI, float* __restrict__ dinv,
                             float* __restrict__ vA, float* __restrict__ vB, int N) {
    int i = blockIdx.x * blockDim.x + threadIdx.x;
    if (i < N) {
        float d = (float)(degI[i] + 1);   // + self loop
        dinv[i] = rsqrtf(d);
    } else if (i == N) {
        dinv[N] = 0.0f;
        vA[N] = 0.0f;
        vB[N] = 0.0f;
    }
}

// rows padded to multiple of 4 slots (pad entries -> src N, w[N]=0)
__global__ __launch_bounds__(256) void scan1_kernel(const int* __restrict__ degI,
                                                    int* __restrict__ rowptr,
                                                    int* __restrict__ blockSums, int N) {
    __shared__ int s[256];
    int t = threadIdx.x;
    int idx = blockIdx.x * 256 + t;
    s[t] = (idx < N) ? ((degI[idx] + 3) & ~3) : 0;
    __syncthreads();
    for (int off = 1; off < 256; off <<= 1) {
        int x = (t >= off) ? s[t - off] : 0;
        __syncthreads();
        s[t] += x;
        __syncthreads();
    }
    if (idx < N) rowptr[idx + 1] = s[t];
    if (t == 255) blockSums[blockIdx.x] = s[255];
    if (blockIdx.x == 0 && t == 0) rowptr[0] = 0;
}

__global__ __launch_bounds__(256) void scan2_kernel(int* __restrict__ blockSums, int nB) {
    __shared__ int s[256];
    int t = threadIdx.x;
    s[t] = (t < nB) ? blockSums[t] : 0;
    __syncthreads();
    for (int off = 1; off < 256; off <<= 1) {
        int x = (t >= off) ? s[t - off] : 0;
        __syncthreads();
        s[t] += x;
        __syncthreads();
    }
    if (t < nB) blockSums[t] = (t == 0) ? 0 : s[t - 1];
}

__global__ void scan3_kernel(int* __restrict__ rowptr, const int* __restrict__ blockSums,
                             int N) {
    int idx = blockIdx.x * 256 + threadIdx.x;
    if (idx < N) rowptr[idx + 1] += blockSums[blockIdx.x];
}

// fill edata with the zero-sink index N (pads read w[N] = 0)
__global__ void fillu_kernel(unsigned int* __restrict__ p, unsigned int val, int n) {
    int i = blockIdx.x * blockDim.x + threadIdx.x;
    if (i < n) p[i] = val;
}

// edata[p] = src (u16) — norm is folded into w = dinv.z
__global__ void scatter_kernel(const int* __restrict__ src, const int* __restrict__ dst,
                               const int* __restrict__ rowptr, int* __restrict__ rowctr,
                               unsigned short* __restrict__ edata, int E) {
    int e = blockIdx.x * blockDim.x + threadIdx.x;
    if (e < E) {
        int d = dst[e];
        int p = rowptr[d] + atomicAdd(&rowctr[d], 1);
        edata[p] = (unsigned short)src[e];
    }
}

// ---------------- degree-sorted permutation (counting sort, 256 buckets) -----
// Waves process 8 nodes in lockstep; trip count = max degree in the wave.
// Sorting nodes by padded degree makes the 8 groups uniform -> no masked waste.

__global__ void deghist_kernel(const int* __restrict__ rowptr, int* __restrict__ h256,
                               int N) {
    int i = blockIdx.x * blockDim.x + threadIdx.x;
    if (i < N) {
        int it = (rowptr[i + 1] - rowptr[i]) >> 2;   // iterations (len/4)
        atomicAdd(&h256[it > 255 ? 255 : it], 1);
    }
}

__global__ __launch_bounds__(256) void degscan_kernel(int* __restrict__ h256) {
    __shared__ int s[256];
    int t = threadIdx.x;
    s[t] = h256[t];
    __syncthreads();
    for (int off = 1; off < 256; off <<= 1) {
        int x = (t >= off) ? s[t - off] : 0;
        __syncthreads();
        s[t] += x;
        __syncthreads();
    }
    h256[t] = (t == 0) ? 0 : s[t - 1];              // exclusive prefix
}

__global__ void permscat_kernel(const int* __restrict__ rowptr, int* __restrict__ h256,
                                int* __restrict__ perm, int N) {
    int i = blockIdx.x * blockDim.x + threadIdx.x;
    if (i < N) {
        int it = (rowptr[i + 1] - rowptr[i]) >> 2;
        int p = atomicAdd(&h256[it > 255 ? 255 : it], 1);
        perm[p] = i;
    }
}

// ---------------- prep: w0 = (h)(dinv*x), ah' = (h)(alpha*dinv*x); zero row N --

__global__ void prep_kernel(const float* __restrict__ x, const float* __restrict__ dinv,
                            half_t* __restrict__ z16A, half_t* __restrict__ z16B,
                            half_t* __restrict__ ah16, int N) {
    int i = blockIdx.x * blockDim.x + threadIdx.x;   // float4 groups
    int nvec = (N + 1) * 16;
    if (i >= nvec) return;
    int row = i >> 4;
    if (row < N) {
        float4 v = reinterpret_cast<const float4*>(x)[i];
        float di = dinv[row];
        half4v z;
        z.x = (half_t)(di * v.x); z.y = (half_t)(di * v.y);
        z.z = (half_t)(di * v.z); z.w = (half_t)(di * v.w);
        reinterpret_cast<half4v*>(z16A)[i] = z;
        half4v a;
        a.x = (half_t)(PROP_ALPHA * di * v.x); a.y = (half_t)(PROP_ALPHA * di * v.y);
        a.z = (half_t)(PROP_ALPHA * di * v.z); a.w = (half_t)(PROP_ALPHA * di * v.w);
        reinterpret_cast<half4v*>(ah16)[i] = a;
    } else {
        half4v zz = {(half_t)0.f, (half_t)0.f, (half_t)0.f, (half_t)0.f};
        reinterpret_cast<half4v*>(z16A)[i] = zz;   // zero sink row for pads
        reinterpret_cast<half4v*>(z16B)[i] = zz;
    }
}

// ---------------- MFMA MLP (verified round 9) ----------------
// h2 = relu(z@W3 + v*b3^T)@W4 + b4 via v_mfma_f32_16x16x32_f16.

__global__ __launch_bounds__(256) void mfmamlp_kernel(const half_t* __restrict__ zx,
                                                      const float* __restrict__ vw,
                                                      const float* __restrict__ dinv,
                                                      const float* __restrict__ W3,
                                                      const float* __restrict__ b3,
                                                      const float* __restrict__ W4,
                                                      const float* __restrict__ b4,
                                                      half_t* __restrict__ z16o,
                                                      half_t* __restrict__ ah16o,
                                                      int N) {
    __shared__ half_t W3T[128 * 72];       // [outcol][k], pad 64->72
    __shared__ half_t W4T[64 * 136];       // [outcol][k], pad 128->136
    __shared__ half_t h1s[4][16 * 136];    // per-wave [row][k], pad 128->136
    __shared__ float vds[4][16];           // per-wave v = vw/dinv
    __shared__ float dds[4][16];           // per-wave dinv

    int t = threadIdx.x;
    int wv = t >> 6, lane = t & 63;
    int ln16 = lane & 15, kg = lane >> 4;  // kg = k-group 0..3
    int r0w = blockIdx.x * 64 + wv * 16;

    for (int idx = t; idx < 64 * 128; idx += 256) {   // W3 [64k][128c]
        int k = idx >> 7, c = idx & 127;
        W3T[c * 72 + k] = (half_t)W3[idx];
    }
    for (int idx = t; idx < 128 * 64; idx += 256) {   // W4 [128k][64c]
        int k = idx >> 6, c = idx & 63;
        W4T[c * 136 + k] = (half_t)W4[idx];
    }
    if (lane < 16) {
        int r = r0w + lane;
        float di = (r < N) ? dinv[r] : 0.0f;
        dds[wv][lane] = di;
        vds[wv][lane] = (r < N && di > 0.0f) ? vw[r] / di : 0.0f;
    }
    __syncthreads();

    // ---- A1 frags: z = w/dinv, fp16, clamped to sink row N for tail ----
    int rowg = r0w + ln16;
    int rowc = (rowg < N) ? rowg : N;                 // sink row = zeros
    float rds = (rowg < N) ? 1.0f / dinv[rowg] : 0.0f;
    half8v a1[2];
    #pragma unroll
    for (int h = 0; h < 2; ++h) {
        half8v w8 = *reinterpret_cast<const half8v*>(
            &zx[(size_t)rowc * 64 + h * 32 + kg * 8]);
        half8v s;
        #pragma unroll
        for (int j = 0; j < 8; ++j) s[j] = (half_t)((float)w8[j] * rds);
        a1[h] = s;
    }

    // ---- layer 1: h1 = relu(z@W3 + v*b3^T), 8 col-tiles x (K=64) ----
    #pragma unroll
    for (int ct = 0; ct < 8; ++ct) {
        float b3c = b3[ct * 16 + ln16];
        f32x4 acc;
        #pragma unroll
        for (int r = 0; r < 4; ++r) acc[r] = vds[wv][kg * 4 + r] * b3c;
        const half_t* wbase = &W3T[(ct * 16 + ln16) * 72 + kg * 8];
        half8v b10 = *reinterpret_cast<const half8v*>(wbase);
        half8v b11 = *reinterpret_cast<const half8v*>(wbase + 32);
        acc = __builtin_amdgcn_mfma_f32_16x16x32_f16(a1[0], b10, acc, 0, 0, 0);
        acc = __builtin_amdgcn_mfma_f32_16x16x32_f16(a1[1], b11, acc, 0, 0, 0);
        #pragma unroll
        for (int r = 0; r < 4; ++r)
            h1s[wv][(kg * 4 + r) * 136 + ct * 16 + ln16] =
                (half_t)fmaxf(acc[r], 0.0f);
    }

    // ---- layer 2: h2 = h1@W4 + b4, 4 col-tiles x (K=128) ----
    #pragma unroll
    for (int ct2 = 0; ct2 < 4; ++ct2) {
        float b4c = b4[ct2 * 16 + ln16];
        f32x4 acc = {b4c, b4c, b4c, b4c};
        #pragma unroll
        for (int kh = 0; kh < 4; ++kh) {
            half8v a2 = *reinterpret_cast<const half8v*>(
                &h1s[wv][ln16 * 136 + kh * 32 + kg * 8]);
            half8v b2 = *reinterpret_cast<const half8v*>(
                &W4T[(ct2 * 16 + ln16) * 136 + kh * 32 + kg * 8]);
            acc = __builtin_amdgcn_mfma_f32_16x16x32_f16(a2, b2, acc, 0, 0, 0);
        }
        #pragma unroll
        for (int r = 0; r < 4; ++r) {
            int row = kg * 4 + r;
            int gr = r0w + row;
            if (gr < N) {
                float di = dds[wv][row];
                float val = acc[r];
                size_t base = (size_t)gr * 64 + ct2 * 16 + ln16;
                z16o[base] = (half_t)(di * val);
                ah16o[base] = (half_t)(PROP_ALPHA * di * val);
            }
        }
    }
}

// ---------------- propagation: w-state, group-per-node, degree-sorted --------
// w_new[d] = (1-a)*dinv[d]^2*(sum_{s in N(d)} w[s] + w[d]) + ah'[d].
// 8-lane group = 1 node, node id via degree-sorted perm -> all 8 groups in a
// wave have ~equal trip counts (no exec-mask idle iterations).

template <bool WITHV>
__global__ __launch_bounds__(256, 8) void prop_kernel(
        const half_t* __restrict__ zin, const half_t* __restrict__ ah16,
        const int* __restrict__ rowptr, const unsigned short* __restrict__ edata,
        const float* __restrict__ dinv, const int* __restrict__ perm,
        half_t* __restrict__ zout, float* __restrict__ outF,
        const float* __restrict__ vin, float* __restrict__ vout,
        int N, int lastOut) {
    const int t = threadIdx.x;
    const int grp = t >> 3;               // node group 0..31 in block
    const int l8 = t & 7;                 // lane within group
    const int c = l8 << 3;                // channel base (8 ch, 16 B)
    int gid = blockIdx.x * 32 + grp;
    if (gid >= N) return;                 // no barriers below: safe
    int node = perm[gid];                 // degree-sorted assignment (bcast load)

    int beg = rowptr[node];
    int end = rowptr[node + 1];           // end-beg multiple of 4
    size_t selfbase = (size_t)node * 64 + c;

    half8v wself = *reinterpret_cast<const half8v*>(&zin[selfbase]);
    half8v ahh = *reinterpret_cast<const half8v*>(&ah16[selfbase]);
    float di = dinv[node];

    float acc[8];
    #pragma unroll
    for (int j = 0; j < 8; ++j) acc[j] = (float)wself[j];   // self term
    float vacc = WITHV ? vin[node] : 0.0f;                  // self vw

    for (int e = beg; e < end; e += 4) {
        ushort4 ss = *reinterpret_cast<const ushort4*>(&edata[e]);  // group-bcast
        half8v z0 = *reinterpret_cast<const half8v*>(&zin[(size_t)ss.x * 64 + c]);
        half8v z1 = *reinterpret_cast<const half8v*>(&zin[(size_t)ss.y * 64 + c]);
        half8v z2 = *reinterpret_cast<const half8v*>(&zin[(size_t)ss.z * 64 + c]);
        half8v z3 = *reinterpret_cast<const half8v*>(&zin[(size_t)ss.w * 64 + c]);
        if (WITHV)
            vacc += (vin[ss.x] + vin[ss.y]) + (vin[ss.z] + vin[ss.w]);
        #pragma unroll
        for (int j = 0; j < 8; ++j) {
            float p0 = (float)z0[j] + (float)z1[j];
            float p1 = (float)z2[j] + (float)z3[j];
            acc[j] += p0 + p1;
        }
    }

    const float om = 1.0f - PROP_ALPHA;
    float dd = di * di;
    if (!lastOut) {
        half8v o;
        #pragma unroll
        for (int j = 0; j < 8; ++j)
            o[j] = (half_t)(om * dd * acc[j] + (float)ahh[j]);
        *reinterpret_cast<half8v*>(&zout[selfbase]) = o;
    } else {
        float rd = 1.0f / di;             // z_out = (1-a)*dinv*S + ah'/dinv
        float r[8];
        #pragma unroll
        for (int j = 0; j < 8; ++j)
            r[j] = om * di * acc[j] + (float)ahh[j] * rd;
        float4 o0 = {r[0], r[1], r[2], r[3]};
        float4 o1 = {r[4], r[5], r[6], r[7]};
        *reinterpret_cast<float4*>(&outF[selfbase]) = o0;
        *reinterpret_cast<float4*>(&outF[selfbase + 4]) = o1;
    }
    if (WITHV && l8 == 0)
        vout[node] = om * dd * vacc + PROP_ALPHA * di;
}

// ---------------- launch ----------------

extern "C" void kernel_launch(void* const* d_in, const int* in_sizes, int n_in,
                              void* d_out, int out_size, void* d_ws, size_t ws_size,
                              hipStream_t stream) {
    const float* x  = (const float*)d_in[0];
    const int*   ei = (const int*)d_in[1];
    const float* W3 = (const float*)d_in[2];
    const float* b3 = (const float*)d_in[3];
    const float* W4 = (const float*)d_in[4];
    const float* b4 = (const float*)d_in[5];
    float* out = (float*)d_out;

    int N = in_sizes[0] / 64;   // IN_CH = 64 ; u16 edata requires N < 65536
    int E = in_sizes[1] / 2;
    const int* srcA = ei;
    const int* dstA = ei + E;

    char* ws = (char*)d_ws;
    size_t off = 0;
    auto alloc = [&](size_t bytes) -> void* {
        void* p = ws + off;
        off = (off + bytes + 255) & ~(size_t)255;
        return p;
    };

    int nScanB = (N + 255) / 256;
    size_t slotsMax = (size_t)E + 4 * (size_t)N;    // upper bound incl. x4 padding

    int*    degI   = (int*)alloc((size_t)N * 4);
    int*    rowptr = (int*)alloc(((size_t)N + 1) * 4);
    int*    rowctr = (int*)alloc((size_t)N * 4);
    int*    bsums  = (int*)alloc((size_t)nScanB * 4);
    int*    h256   = (int*)alloc(256 * 4);
    int*    perm   = (int*)alloc((size_t)N * 4);
    float*  dinv   = (float*)alloc(((size_t)N + 1) * 4);
    unsigned short* edata = (unsigned short*)alloc(slotsMax * 2 + 16);
    float*  vA     = (float*)alloc(((size_t)N + 1) * 4);
    float*  vB     = (float*)alloc(((size_t)N + 1) * 4);
    half_t* z16A   = (half_t*)alloc(((size_t)N + 1) * 64 * 2);
    half_t* z16B   = (half_t*)alloc(((size_t)N + 1) * 64 * 2);
    half_t* ah16   = (half_t*)alloc(((size_t)N + 1) * 64 * 2);

    hipMemsetAsync(degI, 0, (size_t)N * 4, stream);
    hipMemsetAsync(rowctr, 0, (size_t)N * 4, stream);
    hipMemsetAsync(h256, 0, 256 * 4, stream);

    // --- CSR build (rows padded to x4; pads = sink node N) ---
    int nFill = (int)((slotsMax + 1) / 2);
    unsigned int fillv = ((unsigned int)N << 16) | (unsigned int)N;
    fillu_kernel<<<(nFill + 255) / 256, 256, 0, stream>>>((unsigned int*)edata, fillv, nFill);
    hist_kernel<<<(E + 255) / 256, 256, 0, stream>>>(dstA, degI, E);
    dinvz_kernel<<<(N + 256) / 256, 256, 0, stream>>>(degI, dinv, vA, vB, N);
    scan1_kernel<<<nScanB, 256, 0, stream>>>(degI, rowptr, bsums, N);
    scan2_kernel<<<1, 256, 0, stream>>>(bsums, nScanB);
    scan3_kernel<<<nScanB, 256, 0, stream>>>(rowptr, bsums, N);
    scatter_kernel<<<(E + 255) / 256, 256, 0, stream>>>(srcA, dstA, rowptr, rowctr,
                                                        edata, E);
    // degree-sorted perm (counting sort, 256 iteration-count buckets)
    deghist_kernel<<<nScanB, 256, 0, stream>>>(rowptr, h256, N);
    degscan_kernel<<<1, 256, 0, stream>>>(h256);
    permscat_kernel<<<nScanB, 256, 0, stream>>>(rowptr, h256, perm, N);

    int nvec = (N + 1) * 16;
    int propBlocks = (N + 31) / 32;        // 1 node / 8-lane group, 32 nodes/block

    // --- phase 1: w = dinv.x prepped; 10 steps; v tracked as vw ---
    prep_kernel<<<(nvec + 255) / 256, 256, 0, stream>>>(x, dinv, z16A, z16B, ah16, N);
    for (int s = 0; s < PROP_KSTEPS; ++s) {
        const half_t* zi = (s & 1) ? z16B : z16A;
        half_t*       zo = (s & 1) ? z16A : z16B;
        const float*  vi = (s == 0) ? dinv : ((s & 1) ? vA : vB);
        float*        vo = (s & 1) ? vB : vA;
        prop_kernel<true><<<propBlocks, 256, 0, stream>>>(
            zi, ah16, rowptr, edata, dinv, perm, zo, nullptr, vi, vo, N, 0);
    }
    // s0 A->B (vo=vA), s1 B->A (vo=vB), ..., s9 B->A (vo=vB): w10 in z16A, vw10 in vB

    // --- MFMA MLP: z16A,vB -> z16B = w' = dinv*h2, ah16 = alpha*dinv*h2 ---
    mfmamlp_kernel<<<(N + 63) / 64, 256, 0, stream>>>(z16A, vB, dinv, W3, b3, W4, b4,
                                                      z16B, ah16, N);

    // --- phase 2: 10 steps from z16B; last step writes fp32 out ---
    for (int s = 0; s < PROP_KSTEPS; ++s) {
        const half_t* zi = (s & 1) ? z16A : z16B;
        half_t*       zo = (s & 1) ? z16B : z16A;
        int last = (s == PROP_KSTEPS - 1) ? 1 : 0;
        prop_kernel<false><<<propBlocks, 256, 0, stream>>>(
            zi, ah16, rowptr, edata, dinv, perm, zo, out, nullptr, nullptr, N, last);
    }
}

// Round 11
// 516.226 us; speedup vs baseline: 2.1604x; 2.1604x over previous
//
#include <hip/hip_runtime.h>

#define PROP_ALPHA 0.1f
#define PROP_KSTEPS 10

typedef _Float16 half_t;
typedef __attribute__((ext_vector_type(4))) _Float16 half4v;
typedef __attribute__((ext_vector_type(8))) _Float16 half8v;
typedef __attribute__((ext_vector_type(4))) float f32x4;

// ---------------- CSR build ----------------

__global__ void hist_kernel(const int* __restrict__ dst, int* __restrict__ degI, int E) {
    int e = blockIdx.x * blockDim.x + threadIdx.x;
    if (e < E) atomicAdd(&degI[dst[e]], 1);
}

// dinv over N+1 (row N = zero sink for pad slots); also zero vA[N]/vB[N]
__global__ void dinvz_kernel(const int* __restrict__ degI, float* __restrict__ dinv,
                             float* __restrict__ vA, float* __restrict__ vB, int N) {
    int i = blockIdx.x * blockDim.x + threadIdx.x;
    if (i < N) {
        float d = (float)(degI[i] + 1);   // + self loop
        dinv[i] = rsqrtf(d);
    } else if (i == N) {
        dinv[N] = 0.0f;
        vA[N] = 0.0f;
        vB[N] = 0.0f;
    }
}

// rows padded to multiple of 4 slots (pad entries -> src N, w[N]=0)
__global__ __launch_bounds__(256) void scan1_kernel(const int* __restrict__ degI,
                                                    int* __restrict__ rowptr,
                                                    int* __restrict__ blockSums, int N) {
    __shared__ int s[256];
    int t = threadIdx.x;
    int idx = blockIdx.x * 256 + t;
    s[t] = (idx < N) ? ((degI[idx] + 3) & ~3) : 0;
    __syncthreads();
    for (int off = 1; off < 256; off <<= 1) {
        int x = (t >= off) ? s[t - off] : 0;
        __syncthreads();
        s[t] += x;
        __syncthreads();
    }
    if (idx < N) rowptr[idx + 1] = s[t];
    if (t == 255) blockSums[blockIdx.x] = s[255];
    if (blockIdx.x == 0 && t == 0) rowptr[0] = 0;
}

__global__ __launch_bounds__(256) void scan2_kernel(int* __restrict__ blockSums, int nB) {
    __shared__ int s[256];
    int t = threadIdx.x;
    s[t] = (t < nB) ? blockSums[t] : 0;
    __syncthreads();
    for (int off = 1; off < 256; off <<= 1) {
        int x = (t >= off) ? s[t - off] : 0;
        __syncthreads();
        s[t] += x;
        __syncthreads();
    }
    if (t < nB) blockSums[t] = (t == 0) ? 0 : s[t - 1];
}

__global__ void scan3_kernel(int* __restrict__ rowptr, const int* __restrict__ blockSums,
                             int N) {
    int idx = blockIdx.x * 256 + threadIdx.x;
    if (idx < N) rowptr[idx + 1] += blockSums[blockIdx.x];
}

// fill edata with the zero-sink index N (pads read w[N] = 0)
__global__ void fillu_kernel(unsigned int* __restrict__ p, unsigned int val, int n) {
    int i = blockIdx.x * blockDim.x + threadIdx.x;
    if (i < n) p[i] = val;
}

// edata[p] = src (u16) — norm is folded into w = dinv.z
__global__ void scatter_kernel(const int* __restrict__ src, const int* __restrict__ dst,
                               const int* __restrict__ rowptr, int* __restrict__ rowctr,
                               unsigned short* __restrict__ edata, int E) {
    int e = blockIdx.x * blockDim.x + threadIdx.x;
    if (e < E) {
        int d = dst[e];
        int p = rowptr[d] + atomicAdd(&rowctr[d], 1);
        edata[p] = (unsigned short)src[e];
    }
}

// ---------------- prep: w0 = (h)(dinv*x), ah' = (h)(alpha*dinv*x); zero row N --

__global__ void prep_kernel(const float* __restrict__ x, const float* __restrict__ dinv,
                            half_t* __restrict__ z16A, half_t* __restrict__ z16B,
                            half_t* __restrict__ ah16, int N) {
    int i = blockIdx.x * blockDim.x + threadIdx.x;   // float4 groups
    int nvec = (N + 1) * 16;
    if (i >= nvec) return;
    int row = i >> 4;
    if (row < N) {
        float4 v = reinterpret_cast<const float4*>(x)[i];
        float di = dinv[row];
        half4v z;
        z.x = (half_t)(di * v.x); z.y = (half_t)(di * v.y);
        z.z = (half_t)(di * v.z); z.w = (half_t)(di * v.w);
        reinterpret_cast<half4v*>(z16A)[i] = z;
        half4v a;
        a.x = (half_t)(PROP_ALPHA * di * v.x); a.y = (half_t)(PROP_ALPHA * di * v.y);
        a.z = (half_t)(PROP_ALPHA * di * v.z); a.w = (half_t)(PROP_ALPHA * di * v.w);
        reinterpret_cast<half4v*>(ah16)[i] = a;
    } else {
        half4v zz = {(half_t)0.f, (half_t)0.f, (half_t)0.f, (half_t)0.f};
        reinterpret_cast<half4v*>(z16A)[i] = zz;   // zero sink row for pads
        reinterpret_cast<half4v*>(z16B)[i] = zz;
    }
}

// ---------------- MFMA MLP (verified round 9, ~15 us) ----------------
// h2 = relu(z@W3 + v*b3^T)@W4 + b4 via v_mfma_f32_16x16x32_f16.
// Block = 4 waves x 16-node strips. A: row=lane&15, k=(lane>>4)*8+i;
// B: col=lane&15, same k; C/D: col=lane&15, row=(lane>>4)*4+reg [m89].
// v*b3^T folded into MFMA C-init. Weights fp16-transposed in LDS (pads 72/136).

__global__ __launch_bounds__(256) void mfmamlp_kernel(const half_t* __restrict__ zx,
                                                      const float* __restrict__ vw,
                                                      const float* __restrict__ dinv,
                                                      const float* __restrict__ W3,
                                                      const float* __restrict__ b3,
                                                      const float* __restrict__ W4,
                                                      const float* __restrict__ b4,
                                                      half_t* __restrict__ z16o,
                                                      half_t* __restrict__ ah16o,
                                                      int N) {
    __shared__ half_t W3T[128 * 72];       // [outcol][k], pad 64->72
    __shared__ half_t W4T[64 * 136];       // [outcol][k], pad 128->136
    __shared__ half_t h1s[4][16 * 136];    // per-wave [row][k], pad 128->136
    __shared__ float vds[4][16];           // per-wave v = vw/dinv
    __shared__ float dds[4][16];           // per-wave dinv

    int t = threadIdx.x;
    int wv = t >> 6, lane = t & 63;
    int ln16 = lane & 15, kg = lane >> 4;  // kg = k-group 0..3
    int r0w = blockIdx.x * 64 + wv * 16;

    for (int idx = t; idx < 64 * 128; idx += 256) {   // W3 [64k][128c]
        int k = idx >> 7, c = idx & 127;
        W3T[c * 72 + k] = (half_t)W3[idx];
    }
    for (int idx = t; idx < 128 * 64; idx += 256) {   // W4 [128k][64c]
        int k = idx >> 6, c = idx & 63;
        W4T[c * 136 + k] = (half_t)W4[idx];
    }
    if (lane < 16) {
        int r = r0w + lane;
        float di = (r < N) ? dinv[r] : 0.0f;
        dds[wv][lane] = di;
        vds[wv][lane] = (r < N && di > 0.0f) ? vw[r] / di : 0.0f;
    }
    __syncthreads();

    // ---- A1 frags: z = w/dinv, fp16, clamped to sink row N for tail ----
    int rowg = r0w + ln16;
    int rowc = (rowg < N) ? rowg : N;                 // sink row = zeros
    float rds = (rowg < N) ? 1.0f / dinv[rowg] : 0.0f;
    half8v a1[2];
    #pragma unroll
    for (int h = 0; h < 2; ++h) {
        half8v w8 = *reinterpret_cast<const half8v*>(
            &zx[(size_t)rowc * 64 + h * 32 + kg * 8]);
        half8v s;
        #pragma unroll
        for (int j = 0; j < 8; ++j) s[j] = (half_t)((float)w8[j] * rds);
        a1[h] = s;
    }

    // ---- layer 1: h1 = relu(z@W3 + v*b3^T), 8 col-tiles x (K=64) ----
    #pragma unroll
    for (int ct = 0; ct < 8; ++ct) {
        float b3c = b3[ct * 16 + ln16];
        f32x4 acc;
        #pragma unroll
        for (int r = 0; r < 4; ++r) acc[r] = vds[wv][kg * 4 + r] * b3c;
        const half_t* wbase = &W3T[(ct * 16 + ln16) * 72 + kg * 8];
        half8v b10 = *reinterpret_cast<const half8v*>(wbase);
        half8v b11 = *reinterpret_cast<const half8v*>(wbase + 32);
        acc = __builtin_amdgcn_mfma_f32_16x16x32_f16(a1[0], b10, acc, 0, 0, 0);
        acc = __builtin_amdgcn_mfma_f32_16x16x32_f16(a1[1], b11, acc, 0, 0, 0);
        #pragma unroll
        for (int r = 0; r < 4; ++r)
            h1s[wv][(kg * 4 + r) * 136 + ct * 16 + ln16] =
                (half_t)fmaxf(acc[r], 0.0f);
    }

    // ---- layer 2: h2 = h1@W4 + b4, 4 col-tiles x (K=128) ----
    #pragma unroll
    for (int ct2 = 0; ct2 < 4; ++ct2) {
        float b4c = b4[ct2 * 16 + ln16];
        f32x4 acc = {b4c, b4c, b4c, b4c};
        #pragma unroll
        for (int kh = 0; kh < 4; ++kh) {
            half8v a2 = *reinterpret_cast<const half8v*>(
                &h1s[wv][ln16 * 136 + kh * 32 + kg * 8]);
            half8v b2 = *reinterpret_cast<const half8v*>(
                &W4T[(ct2 * 16 + ln16) * 136 + kh * 32 + kg * 8]);
            acc = __builtin_amdgcn_mfma_f32_16x16x32_f16(a2, b2, acc, 0, 0, 0);
        }
        #pragma unroll
        for (int r = 0; r < 4; ++r) {
            int row = kg * 4 + r;
            int gr = r0w + row;
            if (gr < N) {
                float di = dds[wv][row];
                float val = acc[r];
                size_t base = (size_t)gr * 64 + ct2 * 16 + ln16;
                z16o[base] = (half_t)(di * val);
                ah16o[base] = (half_t)(PROP_ALPHA * di * val);
            }
        }
    }
}

// ---------------- propagation: w-state, group-per-node (measured best) -------
// w_new[d] = (1-a)*dinv[d]^2*(sum_{s in N(d)} w[s] + w[d]) + ah'[d].
// 8-lane group = 1 node. Per 4 edges: ONE ushort4 edata load (group-bcast) +
// 4 row-gathers (each 8x16 B = one 128 B line, fully consumed).
// ~22 us/step = the random-line service floor: 5 structural variants
// (pair-pull, plane-split, 4-deep, 8-deep, degree-sorted) all converge here.

template <bool WITHV>
__global__ __launch_bounds__(256, 8) void prop_kernel(
        const half_t* __restrict__ zin, const half_t* __restrict__ ah16,
        const int* __restrict__ rowptr, const unsigned short* __restrict__ edata,
        const float* __restrict__ dinv,
        half_t* __restrict__ zout, float* __restrict__ outF,
        const float* __restrict__ vin, float* __restrict__ vout,
        int N, int lastOut) {
    const int t = threadIdx.x;
    const int grp = t >> 3;               // node group 0..31 in block
    const int l8 = t & 7;                 // lane within group
    const int c = l8 << 3;                // channel base (8 ch, 16 B)
    int node = blockIdx.x * 32 + grp;
    if (node >= N) return;                // no barriers below: safe

    int beg = rowptr[node];
    int end = rowptr[node + 1];           // end-beg multiple of 4
    size_t selfbase = (size_t)node * 64 + c;

    half8v wself = *reinterpret_cast<const half8v*>(&zin[selfbase]);
    half8v ahh = *reinterpret_cast<const half8v*>(&ah16[selfbase]);
    float di = dinv[node];

    float acc[8];
    #pragma unroll
    for (int j = 0; j < 8; ++j) acc[j] = (float)wself[j];   // self term
    float vacc = WITHV ? vin[node] : 0.0f;                  // self vw

    for (int e = beg; e < end; e += 4) {
        ushort4 ss = *reinterpret_cast<const ushort4*>(&edata[e]);  // group-bcast
        half8v z0 = *reinterpret_cast<const half8v*>(&zin[(size_t)ss.x * 64 + c]);
        half8v z1 = *reinterpret_cast<const half8v*>(&zin[(size_t)ss.y * 64 + c]);
        half8v z2 = *reinterpret_cast<const half8v*>(&zin[(size_t)ss.z * 64 + c]);
        half8v z3 = *reinterpret_cast<const half8v*>(&zin[(size_t)ss.w * 64 + c]);
        if (WITHV)
            vacc += (vin[ss.x] + vin[ss.y]) + (vin[ss.z] + vin[ss.w]);
        #pragma unroll
        for (int j = 0; j < 8; ++j) {
            float p0 = (float)z0[j] + (float)z1[j];
            float p1 = (float)z2[j] + (float)z3[j];
            acc[j] += p0 + p1;
        }
    }

    const float om = 1.0f - PROP_ALPHA;
    float dd = di * di;
    if (!lastOut) {
        half8v o;
        #pragma unroll
        for (int j = 0; j < 8; ++j)
            o[j] = (half_t)(om * dd * acc[j] + (float)ahh[j]);
        *reinterpret_cast<half8v*>(&zout[selfbase]) = o;
    } else {
        float rd = 1.0f / di;             // z_out = (1-a)*dinv*S + ah'/dinv
        float r[8];
        #pragma unroll
        for (int j = 0; j < 8; ++j)
            r[j] = om * di * acc[j] + (float)ahh[j] * rd;
        float4 o0 = {r[0], r[1], r[2], r[3]};
        float4 o1 = {r[4], r[5], r[6], r[7]};
        *reinterpret_cast<float4*>(&outF[selfbase]) = o0;
        *reinterpret_cast<float4*>(&outF[selfbase + 4]) = o1;
    }
    if (WITHV && l8 == 0)
        vout[node] = om * dd * vacc + PROP_ALPHA * di;
}

// ---------------- launch ----------------

extern "C" void kernel_launch(void* const* d_in, const int* in_sizes, int n_in,
                              void* d_out, int out_size, void* d_ws, size_t ws_size,
                              hipStream_t stream) {
    const float* x  = (const float*)d_in[0];
    const int*   ei = (const int*)d_in[1];
    const float* W3 = (const float*)d_in[2];
    const float* b3 = (const float*)d_in[3];
    const float* W4 = (const float*)d_in[4];
    const float* b4 = (const float*)d_in[5];
    float* out = (float*)d_out;

    int N = in_sizes[0] / 64;   // IN_CH = 64 ; u16 edata requires N < 65536
    int E = in_sizes[1] / 2;
    const int* srcA = ei;
    const int* dstA = ei + E;

    char* ws = (char*)d_ws;
    size_t off = 0;
    auto alloc = [&](size_t bytes) -> void* {
        void* p = ws + off;
        off = (off + bytes + 255) & ~(size_t)255;
        return p;
    };

    int nScanB = (N + 255) / 256;
    size_t slotsMax = (size_t)E + 4 * (size_t)N;    // upper bound incl. x4 padding

    int*    degI   = (int*)alloc((size_t)N * 4);
    int*    rowptr = (int*)alloc(((size_t)N + 1) * 4);
    int*    rowctr = (int*)alloc((size_t)N * 4);
    int*    bsums  = (int*)alloc((size_t)nScanB * 4);
    float*  dinv   = (float*)alloc(((size_t)N + 1) * 4);
    unsigned short* edata = (unsigned short*)alloc(slotsMax * 2 + 16);
    float*  vA     = (float*)alloc(((size_t)N + 1) * 4);
    float*  vB     = (float*)alloc(((size_t)N + 1) * 4);
    half_t* z16A   = (half_t*)alloc(((size_t)N + 1) * 64 * 2);
    half_t* z16B   = (half_t*)alloc(((size_t)N + 1) * 64 * 2);
    half_t* ah16   = (half_t*)alloc(((size_t)N + 1) * 64 * 2);

    hipMemsetAsync(degI, 0, (size_t)N * 4, stream);
    hipMemsetAsync(rowctr, 0, (size_t)N * 4, stream);

    // --- CSR build (rows padded to x4; pads = sink node N) ---
    int nFill = (int)((slotsMax + 1) / 2);
    unsigned int fillv = ((unsigned int)N << 16) | (unsigned int)N;
    fillu_kernel<<<(nFill + 255) / 256, 256, 0, stream>>>((unsigned int*)edata, fillv, nFill);
    hist_kernel<<<(E + 255) / 256, 256, 0, stream>>>(dstA, degI, E);
    dinvz_kernel<<<(N + 256) / 256, 256, 0, stream>>>(degI, dinv, vA, vB, N);
    scan1_kernel<<<nScanB, 256, 0, stream>>>(degI, rowptr, bsums, N);
    scan2_kernel<<<1, 256, 0, stream>>>(bsums, nScanB);
    scan3_kernel<<<nScanB, 256, 0, stream>>>(rowptr, bsums, N);
    scatter_kernel<<<(E + 255) / 256, 256, 0, stream>>>(srcA, dstA, rowptr, rowctr,
                                                        edata, E);

    int nvec = (N + 1) * 16;
    int propBlocks = (N + 31) / 32;        // 1 node / 8-lane group, 32 nodes/block

    // --- phase 1: w = dinv.x prepped; 10 steps; v tracked as vw ---
    prep_kernel<<<(nvec + 255) / 256, 256, 0, stream>>>(x, dinv, z16A, z16B, ah16, N);
    for (int s = 0; s < PROP_KSTEPS; ++s) {
        const half_t* zi = (s & 1) ? z16B : z16A;
        half_t*       zo = (s & 1) ? z16A : z16B;
        const float*  vi = (s == 0) ? dinv : ((s & 1) ? vA : vB);
        float*        vo = (s & 1) ? vB : vA;
        prop_kernel<true><<<propBlocks, 256, 0, stream>>>(
            zi, ah16, rowptr, edata, dinv, zo, nullptr, vi, vo, N, 0);
    }
    // s0 A->B (vo=vA), s1 B->A (vo=vB), ..., s9 B->A (vo=vB): w10 in z16A, vw10 in vB

    // --- MFMA MLP: z16A,vB -> z16B = w' = dinv*h2, ah16 = alpha*dinv*h2 ---
    mfmamlp_kernel<<<(N + 63) / 64, 256, 0, stream>>>(z16A, vB, dinv, W3, b3, W4, b4,
                                                      z16B, ah16, N);

    // --- phase 2: 10 steps from z16B; last step writes fp32 out ---
    for (int s = 0; s < PROP_KSTEPS; ++s) {
        const half_t* zi = (s & 1) ? z16A : z16B;
        half_t*       zo = (s & 1) ? z16B : z16A;
        int last = (s == PROP_KSTEPS - 1) ? 1 : 0;
        prop_kernel<false><<<propBlocks, 256, 0, stream>>>(
            zi, ah16, rowptr, edata, dinv, zo, out, nullptr, nullptr, N, last);
    }
}